// Round 6
// baseline (63.674 us; speedup 1.0000x reference)
//
#include <hip/hip_runtime.h>

#define NB 128
#define NQ 1000
#define NG 300
#define NK 4
#define THRESH 0.4f

#define GCHUNKS 4                  // GTs split across 4 blocks per batch
#define GPERB   (NG / GCHUNKS)     // 75 GTs per block
#define CAP     40                 // per-GT LDS candidate capacity

// ---------------------------------------------------------------------------
// Single fused kernel, no workspace (d_ws re-poison costs ~39 us/replay).
//
// Phase 1 (thread <-> query): exact conservative prefilter
//   iou > 0.4  <=>  3.5*inter > pa+ta,  tested as fma(inter,3.5,-0.999pa) >=
//   0.999ta (0.1% margin >> f32 rounding => no true positive dropped; rare
//   false positives in iou~[0.3997,0.4] removed by phase 2's exact math).
//   GT box is read with a WAVE-UNIFORM index from a const __restrict__
//   global pointer -> compiler emits s_load_dwordx4 (scalar K$ pipe), so the
//   inner loop touches LDS only for the 4-byte sta broadcast. (Round-5
//   post-mortem: per-iter ds_read_b128 made the loop LDS-pipe/latency-bound,
//   3.5x over the VALU floor.)
// Phase 2 (8 lanes per GT): exact reference-identical math (full IEEE div,
//   same epsilon/op order) on the staged candidates; top-4 via u64 keys
//   (valbits<<32)|~q == (value desc, index asc), exactly jax.lax.top_k's
//   order; 3-step bitonic merge across the 8 lanes (round-1-validated
//   network); zero-filler indices = smallest query indices not in the
//   positive set. Validated absmax=0.0 in rounds 3/4/5.
// ---------------------------------------------------------------------------
__global__ __launch_bounds__(1024) void fused_matcher(
    const float* __restrict__ logits,      // [B,Q,1]
    const float* __restrict__ pboxes,      // [B,Q,4]
    const float* __restrict__ tboxes,      // [B,G,4]
    float* __restrict__ out_vals,          // [B,G,K]
    float* __restrict__ out_idx,           // [B,G,K] (as float)
    float* __restrict__ out_mask)          // [B,G,K] (0/1 float)
{
    __shared__ float4 spb[1024];               // 16 KB pred boxes
    __shared__ float  sscore[1024];            //  4 KB sigmoid scores
    __shared__ float  sta[GPERB];              // 0.999 * target area
    __shared__ unsigned scnt[GPERB];           // per-GT candidate counts
    __shared__ unsigned short sslot[GPERB][CAP];  // 6 KB candidate q lists

    const int b   = blockIdx.y;
    const int gc  = blockIdx.x;
    const int tid = threadIdx.x;
    const int g0  = gc * GPERB;

    const float4* __restrict__ tb4 =
        reinterpret_cast<const float4*>(tboxes) + (size_t)b * NG + g0;

    // ---- Stage: pred box + score per thread; target areas; counters. ----
    float4 p;
    float  s = 0.0f;
    if (tid < NQ) {
        p = reinterpret_cast<const float4*>(pboxes)[(size_t)b * NQ + tid];
        float x = logits[(size_t)b * NQ + tid];
        s = 1.0f / (1.0f + expf(-x));
    } else {
        p = make_float4(2e9f, 2e9f, 2e9f, 2e9f);  // inter=0, area=0: never passes
    }
    spb[tid]    = p;
    sscore[tid] = s;
    const float pa999 = 0.999f * ((p.z - p.x) * (p.w - p.y));

    if (tid < GPERB) {
        float4 t = tb4[tid];
        sta[tid]  = 0.999f * ((t.z - t.x) * (t.w - t.y));
        scnt[tid] = 0u;
    }
    __syncthreads();

    // ---- Phase 1: prefilter. GT box via scalar loads; 4B LDS broadcast. ----
#pragma unroll 5
    for (int gi = 0; gi < GPERB; ++gi) {
        const float4 tb = tb4[gi];   // uniform index -> s_load_dwordx4
        const float  ta = sta[gi];   // 4B broadcast ds_read

        float ltx = fmaxf(p.x, tb.x);
        float lty = fmaxf(p.y, tb.y);
        float rbx = fminf(p.z, tb.z);
        float rby = fminf(p.w, tb.w);
        float w = fmaxf(rbx - ltx, 0.0f);
        float h = fmaxf(rby - lty, 0.0f);
        float inter = w * h;

        if (fmaf(inter, 3.5f, -pa999) >= ta) {
            unsigned pos = atomicAdd(&scnt[gi], 1u);
            if (pos < CAP) sslot[gi][pos] = (unsigned short)tid;
        }
    }
    __syncthreads();

    // ---- Phase 2: exact select, 8 lanes per GT. ----
    const int grp = tid >> 3;    // 0..127, GT within chunk
    const int l8  = tid & 7;
    if (grp < GPERB) {
        const float4 tb = tb4[grp];   // 8-lane broadcast global read (L1)
        const float tarea = (tb.z - tb.x) * (tb.w - tb.y);
        int n = (int)scnt[grp];
        if (n > CAP) n = CAP;

        unsigned long long k0 = 0ull, k1 = 0ull, k2 = 0ull, k3 = 0ull;
        for (int i = l8; i < n; i += 8) {
            const int q = sslot[grp][i];
            const float4 pp = spb[q];
            float parea = (pp.z - pp.x) * (pp.w - pp.y);
            float ltx = fmaxf(pp.x, tb.x);
            float lty = fmaxf(pp.y, tb.y);
            float rbx = fminf(pp.z, tb.z);
            float rby = fminf(pp.w, tb.w);
            float w = fmaxf(rbx - ltx, 0.0f);
            float h = fmaxf(rby - lty, 0.0f);
            float inter = w * h;
            float uni   = parea + tarea - inter;
            float iou   = inter / (uni + 1e-7f);
            if (iou > THRESH) {
                float val = sscore[q] * iou;
                unsigned long long ck =
                    ((unsigned long long)__float_as_uint(val) << 32) |
                    (unsigned long long)(unsigned)(~(unsigned)q);
                if (ck > k3) {
                    if (ck > k0)      { k3 = k2; k2 = k1; k1 = k0; k0 = ck; }
                    else if (ck > k1) { k3 = k2; k2 = k1; k1 = ck; }
                    else if (ck > k2) { k3 = k2; k2 = ck; }
                    else              { k3 = ck; }
                }
            }
        }

        // Bitonic merge of sorted-4 lists across the 8-lane group.
#define MERGE_STEP(MASK)                                                    \
        {                                                                   \
            unsigned long long p0 = __shfl_xor(k0, MASK, 64);               \
            unsigned long long p1 = __shfl_xor(k1, MASK, 64);               \
            unsigned long long p2 = __shfl_xor(k2, MASK, 64);               \
            unsigned long long p3 = __shfl_xor(k3, MASK, 64);               \
            k0 = k0 > p3 ? k0 : p3;                                         \
            k1 = k1 > p2 ? k1 : p2;                                         \
            k2 = k2 > p1 ? k2 : p1;                                         \
            k3 = k3 > p0 ? k3 : p0;                                         \
            unsigned long long t;                                           \
            if (k0 < k2) { t = k0; k0 = k2; k2 = t; }                       \
            if (k1 < k3) { t = k1; k1 = k3; k3 = t; }                       \
            if (k0 < k1) { t = k0; k0 = k1; k1 = t; }                       \
            if (k2 < k3) { t = k2; k2 = k3; k3 = t; }                       \
        }
        MERGE_STEP(1)
        MERGE_STEP(2)
        MERGE_STEP(4)
#undef MERGE_STEP

        if (l8 == 0) {
            const int iq0 = k0 ? (int)~(unsigned)k0 : -1;
            const int iq1 = k1 ? (int)~(unsigned)k1 : -1;
            const int iq2 = k2 ? (int)~(unsigned)k2 : -1;
            float4 vv, vi, vm;
            float* pv = &vv.x; float* pi_ = &vi.x; float* pm = &vm.x;
            int fill = 0;
#define EMIT(J, KJ)                                                         \
            {                                                               \
                if (KJ != 0ull) {                                           \
                    pv[J]  = __uint_as_float((unsigned)(KJ >> 32));         \
                    pi_[J] = (float)(int)~(unsigned)KJ;                     \
                    pm[J]  = 1.0f;                                          \
                } else {                                                    \
                    while (fill == iq0 || fill == iq1 || fill == iq2)       \
                        ++fill;                                             \
                    pv[J]  = 0.0f;                                          \
                    pi_[J] = (float)fill;                                   \
                    pm[J]  = 0.0f;                                          \
                    ++fill;                                                 \
                }                                                           \
            }
            EMIT(0, k0) EMIT(1, k1) EMIT(2, k2) EMIT(3, k3)
#undef EMIT
            const size_t o4 = (size_t)b * NG + g0 + grp;  // float4 index
            reinterpret_cast<float4*>(out_vals)[o4] = vv;
            reinterpret_cast<float4*>(out_idx)[o4]  = vi;
            reinterpret_cast<float4*>(out_mask)[o4] = vm;
        }
    }
}

extern "C" void kernel_launch(void* const* d_in, const int* in_sizes, int n_in,
                              void* d_out, int out_size, void* d_ws, size_t ws_size,
                              hipStream_t stream) {
    const float* logits = (const float*)d_in[0];  // [128,1000,1]
    const float* pboxes = (const float*)d_in[1];  // [128,1000,4]
    const float* tboxes = (const float*)d_in[2];  // [128,300,4]

    float* out = (float*)d_out;
    const size_t bgk = (size_t)NB * NG * NK;      // 153600
    float* out_vals = out;
    float* out_idx  = out + bgk;
    float* out_mask = out + 2 * bgk;

    dim3 grid(GCHUNKS, NB);                       // (4,128) = 512 blocks
    fused_matcher<<<grid, 1024, 0, stream>>>(logits, pboxes, tboxes,
                                             out_vals, out_idx, out_mask);
}

// Round 7
// 57.928 us; speedup vs baseline: 1.0992x; 1.0992x over previous
//
#include <hip/hip_runtime.h>

#define NB 128
#define NQ 1000
#define NG 300
#define NK 4
#define THRESH 0.4f

#define GCHUNKS 5                  // 300 = 5 x 60 GTs
#define GPERB   60                 // GTs per block = lanes 0..59 of each wave
#define NWAVES  8                  // 512 threads per block
#define QPW     (NQ / NWAVES)      // 125 queries per wave
#define CAP     48                 // per-GT LDS candidate capacity

// ---------------------------------------------------------------------------
// Single fused kernel, no workspace (d_ws re-poison costs ~39 us/replay).
//
// Round-6 post-mortem: ANY per-iteration dependent memory read in the hot
// loop (LDS b128 in r5, "uniform" global load in r6) makes the loop
// pipe/latency-bound, 2-5x over the VALU floor. So: TRANSPOSE. Lane <-> GT
// (box lives in 4 VGPRs for the whole scan), query box is wave-uniform and
// prefetched 5-deep into named registers per stripe (>=5 loads in flight
// even if they compile as vector loads; s_load_dwordx4 if scalarized).
// Inner body = ~12 pure-VALU ops + rarely-taken LDS push.
//
// Phase 1 exact conservative prefilter: iou>0.4 <=> 3.5*inter > pa+ta,
// tested as fma(inter,3.5,-0.999pa) >= 0.999ta (0.1% margin >> f32 rounding
// => no true positive dropped; rare false positives in iou~[0.3997,0.4]
// removed by phase 2's exact math). Passing q pushed to per-GT LDS lists.
// Phase 2 (8 lanes/GT): exact reference-identical math (full IEEE div, same
// epsilon/op order, sigmoid), top-4 via u64 keys (valbits<<32)|~q ==
// (value desc, index asc) = jax.lax.top_k order; 3-step bitonic merge
// (round-1-validated network); zero-filler indices = smallest unused q.
// All protocol pieces validated absmax=0.0 in rounds 3/4/5.
// ---------------------------------------------------------------------------
__global__ __launch_bounds__(512) void fused_matcher(
    const float* __restrict__ logits,      // [B,Q,1]
    const float* __restrict__ pboxes,      // [B,Q,4]
    const float* __restrict__ tboxes,      // [B,G,4]
    float* __restrict__ out_vals,          // [B,G,K]
    float* __restrict__ out_idx,           // [B,G,K] (as float)
    float* __restrict__ out_mask)          // [B,G,K] (0/1 float)
{
    __shared__ unsigned scnt[GPERB];              // per-GT candidate counts
    __shared__ unsigned short sslot[GPERB][CAP];  // per-GT candidate q lists

    const int b    = blockIdx.y;
    const int gc   = blockIdx.x;
    const int tid  = threadIdx.x;
    const int lane = tid & 63;
    const int g0   = gc * GPERB;

    const float4* __restrict__ tb4 =
        reinterpret_cast<const float4*>(tboxes) + (size_t)b * NG + g0;
    const float4* __restrict__ pb4 =
        reinterpret_cast<const float4*>(pboxes) + (size_t)b * NQ;

    if (tid < GPERB) scnt[tid] = 0u;

    // Lane's GT box: one coalesced load, lives in registers for the scan.
    // Dummy box for lanes 60..63: inter=0 and ta=0 -> test is -qa>=0, always
    // false (qa>0 since wh>=0.01), so they never push.
    float4 tg = (lane < GPERB) ? tb4[lane]
                               : make_float4(2e9f, 2e9f, 2e9f, 2e9f);
    const float ta999 = 0.999f * ((tg.z - tg.x) * (tg.w - tg.y));

    __syncthreads();

    // ---- Phase 1: lanes<->GTs, wave scans its 125 queries, 5-deep
    //      register prefetch of the (wave-uniform) query boxes. ----
    const int qw = __builtin_amdgcn_readfirstlane((int)(tid >> 6));
    const float4* __restrict__ qp = pb4 + qw * QPW;
    const int qbase = qw * QPW;

    auto test = [&](const float4 qx, int qidx) {
        float qa999 = 0.999f * ((qx.z - qx.x) * (qx.w - qx.y));
        float ltx = fmaxf(qx.x, tg.x);
        float lty = fmaxf(qx.y, tg.y);
        float rbx = fminf(qx.z, tg.z);
        float rby = fminf(qx.w, tg.w);
        float w = fmaxf(rbx - ltx, 0.0f);
        float h = fmaxf(rby - lty, 0.0f);
        float inter = w * h;
        if (fmaf(inter, 3.5f, -qa999) >= ta999) {
            unsigned pos = atomicAdd(&scnt[lane], 1u);
            if (pos < CAP) sslot[lane][pos] = (unsigned short)qidx;
        }
    };

    for (int j0 = 0; j0 < QPW; j0 += 5) {   // 125 = 25 stripes x 5
        // Issue all 5 loads before any use (named regs: static indexing).
        float4 qA = qp[j0 + 0];
        float4 qB = qp[j0 + 1];
        float4 qC = qp[j0 + 2];
        float4 qD = qp[j0 + 3];
        float4 qE = qp[j0 + 4];
        test(qA, qbase + j0 + 0);
        test(qB, qbase + j0 + 1);
        test(qC, qbase + j0 + 2);
        test(qD, qbase + j0 + 3);
        test(qE, qbase + j0 + 4);
    }
    __syncthreads();

    // ---- Phase 2: exact select, 8 lanes per GT. ----
    const int grp = tid >> 3;    // GT within chunk
    const int l8  = tid & 7;
    if (grp < GPERB) {
        const float4 tb = tb4[grp];   // 8-lane broadcast read (L1/L2)
        const float tarea = (tb.z - tb.x) * (tb.w - tb.y);
        int n = (int)scnt[grp];
        if (n > CAP) n = CAP;
        const float* __restrict__ lg = logits + (size_t)b * NQ;

        unsigned long long k0 = 0ull, k1 = 0ull, k2 = 0ull, k3 = 0ull;
        for (int i = l8; i < n; i += 8) {
            const int q = sslot[grp][i];
            const float4 pp = pb4[q];
            float parea = (pp.z - pp.x) * (pp.w - pp.y);
            float ltx = fmaxf(pp.x, tb.x);
            float lty = fmaxf(pp.y, tb.y);
            float rbx = fminf(pp.z, tb.z);
            float rby = fminf(pp.w, tb.w);
            float w = fmaxf(rbx - ltx, 0.0f);
            float h = fmaxf(rby - lty, 0.0f);
            float inter = w * h;
            float uni   = parea + tarea - inter;
            float iou   = inter / (uni + 1e-7f);
            if (iou > THRESH) {
                float x   = lg[q];
                float sc  = 1.0f / (1.0f + expf(-x));
                float val = sc * iou;
                unsigned long long ck =
                    ((unsigned long long)__float_as_uint(val) << 32) |
                    (unsigned long long)(unsigned)(~(unsigned)q);
                if (ck > k3) {
                    if (ck > k0)      { k3 = k2; k2 = k1; k1 = k0; k0 = ck; }
                    else if (ck > k1) { k3 = k2; k2 = k1; k1 = ck; }
                    else if (ck > k2) { k3 = k2; k2 = ck; }
                    else              { k3 = ck; }
                }
            }
        }

        // Bitonic merge of sorted-4 lists across the 8-lane group
        // (partners share grp, so all participating lanes are active).
#define MERGE_STEP(MASK)                                                    \
        {                                                                   \
            unsigned long long p0 = __shfl_xor(k0, MASK, 64);               \
            unsigned long long p1 = __shfl_xor(k1, MASK, 64);               \
            unsigned long long p2 = __shfl_xor(k2, MASK, 64);               \
            unsigned long long p3 = __shfl_xor(k3, MASK, 64);               \
            k0 = k0 > p3 ? k0 : p3;                                         \
            k1 = k1 > p2 ? k1 : p2;                                         \
            k2 = k2 > p1 ? k2 : p1;                                         \
            k3 = k3 > p0 ? k3 : p0;                                         \
            unsigned long long t;                                           \
            if (k0 < k2) { t = k0; k0 = k2; k2 = t; }                       \
            if (k1 < k3) { t = k1; k1 = k3; k3 = t; }                       \
            if (k0 < k1) { t = k0; k0 = k1; k1 = t; }                       \
            if (k2 < k3) { t = k2; k2 = k3; k3 = t; }                       \
        }
        MERGE_STEP(1)
        MERGE_STEP(2)
        MERGE_STEP(4)
#undef MERGE_STEP

        if (l8 == 0) {
            const int iq0 = k0 ? (int)~(unsigned)k0 : -1;
            const int iq1 = k1 ? (int)~(unsigned)k1 : -1;
            const int iq2 = k2 ? (int)~(unsigned)k2 : -1;
            float4 vv, vi, vm;
            float* pv = &vv.x; float* pi_ = &vi.x; float* pm = &vm.x;
            int fill = 0;
#define EMIT(J, KJ)                                                         \
            {                                                               \
                if (KJ != 0ull) {                                           \
                    pv[J]  = __uint_as_float((unsigned)(KJ >> 32));         \
                    pi_[J] = (float)(int)~(unsigned)KJ;                     \
                    pm[J]  = 1.0f;                                          \
                } else {                                                    \
                    while (fill == iq0 || fill == iq1 || fill == iq2)       \
                        ++fill;                                             \
                    pv[J]  = 0.0f;                                          \
                    pi_[J] = (float)fill;                                   \
                    pm[J]  = 0.0f;                                          \
                    ++fill;                                                 \
                }                                                           \
            }
            EMIT(0, k0) EMIT(1, k1) EMIT(2, k2) EMIT(3, k3)
#undef EMIT
            const size_t o4 = (size_t)b * NG + g0 + grp;  // float4 index
            reinterpret_cast<float4*>(out_vals)[o4] = vv;
            reinterpret_cast<float4*>(out_idx)[o4]  = vi;
            reinterpret_cast<float4*>(out_mask)[o4] = vm;
        }
    }
}

extern "C" void kernel_launch(void* const* d_in, const int* in_sizes, int n_in,
                              void* d_out, int out_size, void* d_ws, size_t ws_size,
                              hipStream_t stream) {
    const float* logits = (const float*)d_in[0];  // [128,1000,1]
    const float* pboxes = (const float*)d_in[1];  // [128,1000,4]
    const float* tboxes = (const float*)d_in[2];  // [128,300,4]

    float* out = (float*)d_out;
    const size_t bgk = (size_t)NB * NG * NK;      // 153600
    float* out_vals = out;
    float* out_idx  = out + bgk;
    float* out_mask = out + 2 * bgk;

    dim3 grid(GCHUNKS, NB);                       // (5,128) = 640 blocks
    fused_matcher<<<grid, 512, 0, stream>>>(logits, pboxes, tboxes,
                                            out_vals, out_idx, out_mask);
}

// Round 8
// 33.270 us; speedup vs baseline: 1.9139x; 1.7412x over previous
//
#include <hip/hip_runtime.h>

#define NB 128
#define NQ 1000
#define NG 300
#define NK 4
#define THRESH 0.4f

#define GCHUNKS  6                 // 300 = 6 x 50 GTs
#define GPERB    50                // GTs per block
#define NTHREADS 256
#define QPT      4                 // queries per thread (in registers)
#define QCAP     24                // per-thread LDS queue capacity
#define CAP      48                // per-GT candidate list capacity

// ---------------------------------------------------------------------------
// Single fused kernel, no workspace (d_ws re-poison costs ~39 us/replay).
//
// Structure lesson from rounds 5/6/7: the hot loop must contain NO dependent
// memory op. Here: 4 query boxes live in registers per thread; the only
// memory op per iteration is ONE broadcast ds_read_b128 of the next GT box,
// software-pipelined one iteration ahead (latency hidden), amortized over 4
// tests; a prefilter pass appends to a per-thread PRIVATE LDS queue column
// (plain ds_write_b16, fire-and-forget -- no atomic, no read-back). The
// per-GT atomic scatter happens once per pass AFTER the loop (~1.6/thread).
//
// Phase 1 exact conservative prefilter: iou>0.4 <=> 3.5*inter > pa+ta,
// tested as fma(inter,3.5,-0.999pa) >= 0.999ta (0.1% margin >> f32 rounding
// => no true positive dropped; rare false positives in iou~[0.3997,0.4]
// removed by phase 2's exact math).
// Phase 2 (4 lanes/GT): exact reference-identical math (full IEEE div, same
// epsilon/op order, sigmoid), top-4 via u64 keys (valbits<<32)|~q ==
// (value desc, index asc) = jax.lax.top_k order; bitonic merge masks 1,2
// (same validated network); zero-filler indices = smallest unused q.
// Protocol validated absmax=0.0 in rounds 3/4/5/6/7.
// ---------------------------------------------------------------------------
__global__ __launch_bounds__(NTHREADS) void fused_matcher(
    const float* __restrict__ logits,      // [B,Q,1]
    const float* __restrict__ pboxes,      // [B,Q,4]
    const float* __restrict__ tboxes,      // [B,G,4]
    float* __restrict__ out_vals,          // [B,G,K]
    float* __restrict__ out_idx,           // [B,G,K] (as float)
    float* __restrict__ out_mask)          // [B,G,K] (0/1 float)
{
    __shared__ float4 stb[GPERB + 1];                 // GT boxes (+sentinel)
    __shared__ unsigned scnt[GPERB];                  // per-GT counts
    __shared__ unsigned short sslot[GPERB][CAP];      // per-GT candidate q's
    __shared__ unsigned short queue[QCAP][NTHREADS];  // per-thread pass queues

    const int b   = blockIdx.y;
    const int gc  = blockIdx.x;
    const int tid = threadIdx.x;
    const int g0  = gc * GPERB;

    const float4* __restrict__ tb4 =
        reinterpret_cast<const float4*>(tboxes) + (size_t)b * NG + g0;
    const float4* __restrict__ pb4 =
        reinterpret_cast<const float4*>(pboxes) + (size_t)b * NQ;

    // ---- Stage: GT boxes to LDS; 4 query boxes to registers. ----
    if (tid < GPERB) {
        stb[tid]  = tb4[tid];
        scnt[tid] = 0u;
    }
    if (tid == 0) stb[GPERB] = make_float4(2e9f, 2e9f, 2e9f, 2e9f);

    const float4 dummy = make_float4(2e9f, 2e9f, 2e9f, 2e9f);
    float4 pA = pb4[tid];                                        // q = tid
    float4 pB = pb4[NTHREADS + tid];                             // q = 256+tid
    float4 pC = pb4[2 * NTHREADS + tid];                         // q = 512+tid
    float4 pD = (3 * NTHREADS + tid < NQ) ? pb4[3 * NTHREADS + tid] : dummy;
    const float aA = 0.999f * ((pA.z - pA.x) * (pA.w - pA.y));
    const float aB = 0.999f * ((pB.z - pB.x) * (pB.w - pB.y));
    const float aC = 0.999f * ((pC.z - pC.x) * (pC.w - pC.y));
    const float aD = 0.999f * ((pD.z - pD.x) * (pD.w - pD.y));

    __syncthreads();

    // ---- Phase 1: 50 iterations, 4 register-resident tests each. ----
    int cnt = 0;
    float4 tc = stb[0];
#define TEST(P, A, SEL)                                                     \
    {                                                                       \
        float ltx = fmaxf(P.x, tc.x);                                       \
        float lty = fmaxf(P.y, tc.y);                                       \
        float rbx = fminf(P.z, tc.z);                                       \
        float rby = fminf(P.w, tc.w);                                       \
        float w = fmaxf(rbx - ltx, 0.0f);                                   \
        float h = fmaxf(rby - lty, 0.0f);                                   \
        float inter = w * h;                                                \
        bool pass = fmaf(inter, 3.5f, -(A)) >= ta999;                       \
        if (pass && cnt < QCAP)                                             \
            queue[cnt][tid] = (unsigned short)((gi << 2) | (SEL));          \
        cnt += pass ? 1 : 0;                                                \
    }
    for (int gi = 0; gi < GPERB; ++gi) {
        float4 tn = stb[gi + 1];   // prefetch next GT box (broadcast read)
        const float ta999 = 0.999f * ((tc.z - tc.x) * (tc.w - tc.y));
        TEST(pA, aA, 0)
        TEST(pB, aB, 1)
        TEST(pC, aC, 2)
        TEST(pD, aD, 3)
        tc = tn;
    }
#undef TEST

    // ---- Drain private queues into per-GT lists (outside hot loop). ----
    const int m = cnt < QCAP ? cnt : QCAP;
    for (int i = 0; i < m; ++i) {
        const int e   = queue[i][tid];
        const int gi  = e >> 2;
        const int q   = (e & 3) * NTHREADS + tid;
        unsigned pos = atomicAdd(&scnt[gi], 1u);
        if (pos < CAP) sslot[gi][pos] = (unsigned short)q;
    }
    __syncthreads();

    // ---- Phase 2: exact select, 4 lanes per GT. ----
    const int grp = tid >> 2;    // GT within chunk
    const int l4  = tid & 3;
    if (grp < GPERB) {
        const float4 tb = stb[grp];
        const float tarea = (tb.z - tb.x) * (tb.w - tb.y);
        int n = (int)scnt[grp];
        if (n > CAP) n = CAP;
        const float* __restrict__ lg = logits + (size_t)b * NQ;

        unsigned long long k0 = 0ull, k1 = 0ull, k2 = 0ull, k3 = 0ull;
        for (int i = l4; i < n; i += 4) {
            const int q = sslot[grp][i];
            const float4 pp = pb4[q];
            float parea = (pp.z - pp.x) * (pp.w - pp.y);
            float ltx = fmaxf(pp.x, tb.x);
            float lty = fmaxf(pp.y, tb.y);
            float rbx = fminf(pp.z, tb.z);
            float rby = fminf(pp.w, tb.w);
            float w = fmaxf(rbx - ltx, 0.0f);
            float h = fmaxf(rby - lty, 0.0f);
            float inter = w * h;
            float uni   = parea + tarea - inter;
            float iou   = inter / (uni + 1e-7f);
            if (iou > THRESH) {
                float x   = lg[q];
                float sc  = 1.0f / (1.0f + expf(-x));
                float val = sc * iou;
                unsigned long long ck =
                    ((unsigned long long)__float_as_uint(val) << 32) |
                    (unsigned long long)(unsigned)(~(unsigned)q);
                if (ck > k3) {
                    if (ck > k0)      { k3 = k2; k2 = k1; k1 = k0; k0 = ck; }
                    else if (ck > k1) { k3 = k2; k2 = k1; k1 = ck; }
                    else if (ck > k2) { k3 = k2; k2 = ck; }
                    else              { k3 = ck; }
                }
            }
        }

        // Bitonic merge of sorted-4 lists across the 4-lane group.
#define MERGE_STEP(MASK)                                                    \
        {                                                                   \
            unsigned long long p0 = __shfl_xor(k0, MASK, 64);               \
            unsigned long long p1 = __shfl_xor(k1, MASK, 64);               \
            unsigned long long p2 = __shfl_xor(k2, MASK, 64);               \
            unsigned long long p3 = __shfl_xor(k3, MASK, 64);               \
            k0 = k0 > p3 ? k0 : p3;                                         \
            k1 = k1 > p2 ? k1 : p2;                                         \
            k2 = k2 > p1 ? k2 : p1;                                         \
            k3 = k3 > p0 ? k3 : p0;                                         \
            unsigned long long t;                                           \
            if (k0 < k2) { t = k0; k0 = k2; k2 = t; }                       \
            if (k1 < k3) { t = k1; k1 = k3; k3 = t; }                       \
            if (k0 < k1) { t = k0; k0 = k1; k1 = t; }                       \
            if (k2 < k3) { t = k2; k2 = k3; k3 = t; }                       \
        }
        MERGE_STEP(1)
        MERGE_STEP(2)
#undef MERGE_STEP

        if (l4 == 0) {
            const int iq0 = k0 ? (int)~(unsigned)k0 : -1;
            const int iq1 = k1 ? (int)~(unsigned)k1 : -1;
            const int iq2 = k2 ? (int)~(unsigned)k2 : -1;
            float4 vv, vi, vm;
            float* pv = &vv.x; float* pi_ = &vi.x; float* pm = &vm.x;
            int fill = 0;
#define EMIT(J, KJ)                                                         \
            {                                                               \
                if (KJ != 0ull) {                                           \
                    pv[J]  = __uint_as_float((unsigned)(KJ >> 32));         \
                    pi_[J] = (float)(int)~(unsigned)KJ;                     \
                    pm[J]  = 1.0f;                                          \
                } else {                                                    \
                    while (fill == iq0 || fill == iq1 || fill == iq2)       \
                        ++fill;                                             \
                    pv[J]  = 0.0f;                                          \
                    pi_[J] = (float)fill;                                   \
                    pm[J]  = 0.0f;                                          \
                    ++fill;                                                 \
                }                                                           \
            }
            EMIT(0, k0) EMIT(1, k1) EMIT(2, k2) EMIT(3, k3)
#undef EMIT
            const size_t o4 = (size_t)b * NG + g0 + grp;  // float4 index
            reinterpret_cast<float4*>(out_vals)[o4] = vv;
            reinterpret_cast<float4*>(out_idx)[o4]  = vi;
            reinterpret_cast<float4*>(out_mask)[o4] = vm;
        }
    }
}

extern "C" void kernel_launch(void* const* d_in, const int* in_sizes, int n_in,
                              void* d_out, int out_size, void* d_ws, size_t ws_size,
                              hipStream_t stream) {
    const float* logits = (const float*)d_in[0];  // [128,1000,1]
    const float* pboxes = (const float*)d_in[1];  // [128,1000,4]
    const float* tboxes = (const float*)d_in[2];  // [128,300,4]

    float* out = (float*)d_out;
    const size_t bgk = (size_t)NB * NG * NK;      // 153600
    float* out_vals = out;
    float* out_idx  = out + bgk;
    float* out_mask = out + 2 * bgk;

    dim3 grid(GCHUNKS, NB);                       // (6,128) = 768 blocks
    fused_matcher<<<grid, NTHREADS, 0, stream>>>(logits, pboxes, tboxes,
                                                 out_vals, out_idx, out_mask);
}